// Round 9
// baseline (132.183 us; speedup 1.0000x reference)
//
#include <hip/hip_runtime.h>
#include <math.h>

#define TOKENS   4096          // B*T = 2*2048
#define CDIM     1024
#define NEXP     8
#define CAP      2048
#define OUT_OFS  8             // used_capacity occupies d_out[0..8)
#define PER_OUT  (TOKENS * NEXP * CAP)   // 67,108,864 elements per big output
#define N4TOTAL  ((2 * PER_OUT + OUT_OFS) / 4)   // 33,554,434 float4, whole buffer

#define GATE_BLOCKS   256
#define TOK_PER_WAVE  4                          // 16 tokens/block, 4 waves
#define FILL_BLOCKS   ((N4TOTAL + 511) / 512)    // 65,537: 2 float4 stores/thread, no loop

// ---------------------------------------------------------------------------
// Kernel 1: fused fill + gating.
//   blocks [0, GATE_BLOCKS): gating for 16 tokens each (no LDS -> no
//     occupancy penalty for fill blocks; w_g reads are L1/L2-hot).
//   blocks [GATE_BLOCKS, GATE_BLOCKS+FILL_BLOCKS): rocclr-fill-shaped zeroing
//     of the WHOLE output: two unlooped float4 stores per thread, huge grid.
// Gating blocks are first so they start immediately and hide under the fill.
// ---------------------------------------------------------------------------
__global__ __launch_bounds__(256) void fill_gate_kernel(const float* __restrict__ x,
                                                        const float* __restrict__ wg,
                                                        int*   __restrict__ top1,
                                                        int*   __restrict__ top2,
                                                        float* __restrict__ p1,
                                                        float* __restrict__ p2,
                                                        float4* __restrict__ out4) {
    if (blockIdx.x >= GATE_BLOCKS) {
        // ---- fill path: exactly rocclr's shape (wide stores, no loop) ----
        const int i = (blockIdx.x - GATE_BLOCKS) * 512 + threadIdx.x;
        const float4 z = make_float4(0.f, 0.f, 0.f, 0.f);
        if (i < N4TOTAL) out4[i] = z;
        const int i2 = i + 256;
        if (i2 < N4TOTAL) out4[i2] = z;
        return;
    }

    // ---- gating path ----
    const int wave = threadIdx.x >> 6;
    const int lane = threadIdx.x & 63;

    for (int tt = 0; tt < TOK_PER_WAVE; ++tt) {
        const int tok = (blockIdx.x * 4 + wave) * TOK_PER_WAVE + tt;
        const float* xr = x + (size_t)tok * CDIM;

        float acc[NEXP];
#pragma unroll
        for (int e = 0; e < NEXP; ++e) acc[e] = 0.f;

#pragma unroll
        for (int i = 0; i < CDIM / 64; ++i) {
            const float xv = xr[lane + 64 * i];
#pragma unroll
            for (int e = 0; e < NEXP; ++e)
                acc[e] = fmaf(xv, wg[e * CDIM + lane + 64 * i], acc[e]);
        }
        // 64-lane tree reduction per expert
#pragma unroll
        for (int e = 0; e < NEXP; ++e) {
            float v = acc[e];
#pragma unroll
            for (int s = 32; s >= 1; s >>= 1) v += __shfl_xor(v, s, 64);
            acc[e] = v;
        }

        if (lane == 0) {
            int e1 = 0; float l1 = acc[0];
#pragma unroll
            for (int e = 1; e < NEXP; ++e)
                if (acc[e] > l1) { l1 = acc[e]; e1 = e; }
            int e2 = -1; float l2 = -INFINITY;
#pragma unroll
            for (int e = 0; e < NEXP; ++e)
                if (e != e1 && acc[e] > l2) { l2 = acc[e]; e2 = e; }
            const float ex = expf(l2 - l1);       // l1 >= l2
            const float denom = 1.f + ex;
            top1[tok] = e1;
            top2[tok] = e2;
            p1[tok] = 1.f / denom;
            p2[tok] = ex / denom;
        }
    }
}

// ---------------------------------------------------------------------------
// Kernel 2: fused scan + scatter, one block of 256 threads.
// Wave 0 does the register-resident sequential-order capacity scan (identical
// algorithm to round 7), writing each assignment's rank into LDS sr[8192]
// (sr[a] for global assignment order a = k*TOKENS + t) and used_capacity to
// out[0..8). After the barrier all 256 threads scatter the <=16K nonzeros.
// ---------------------------------------------------------------------------
__global__ __launch_bounds__(256) void scan_scatter_kernel(const int* __restrict__ top1,
                                                           const int* __restrict__ top2,
                                                           const float* __restrict__ p1,
                                                           const float* __restrict__ p2,
                                                           float* __restrict__ out) {
    __shared__ int sr[2 * TOKENS];         // 32 KiB: rank per assignment
    const int tid = threadIdx.x;

    if (tid < 64) {
        const int lane = tid;              // 0..63; lanes 0..31 -> top1, 32..63 -> top2
        const int* __restrict__ src = (lane < 32) ? (top1 + lane * 128)
                                                  : (top2 + (lane - 32) * 128);
        int4 a[32];
#pragma unroll
        for (int i = 0; i < 32; ++i) a[i] = ((const int4*)src)[i];

        // packed histogram: 8 experts x 8 bits (max 128 per lane fits)
        unsigned long long cnt = 0ull;
#pragma unroll
        for (int i = 0; i < 32; ++i) {
            cnt += 1ull << (a[i].x << 3);
            cnt += 1ull << (a[i].y << 3);
            cnt += 1ull << (a[i].z << 3);
            cnt += 1ull << (a[i].w << 3);
        }
        int c[NEXP];
#pragma unroll
        for (int e = 0; e < NEXP; ++e) c[e] = (int)((cnt >> (e * 8)) & 0xff);

        // per-expert exclusive prefix across lanes + totals
        int off[NEXP], tot[NEXP];
#pragma unroll
        for (int e = 0; e < NEXP; ++e) {
            int v = c[e];
#pragma unroll
            for (int s = 1; s <= 32; s <<= 1) {
                const int u = __shfl_up(v, s, 64);
                if (lane >= s) v += u;
            }
            off[e] = v - c[e];
            tot[e] = __shfl(v, 63, 64);
        }

        // replay from registers, ranks -> LDS (sr[a], a = lane*128 + j)
        int4* __restrict__ dst = (int4*)sr + lane * 32;
#pragma unroll
        for (int i = 0; i < 32; ++i) {
            int4 r;
            int e, rr;
            e = a[i].x; rr = 0;
#pragma unroll
            for (int ee = 0; ee < NEXP; ++ee) if (e == ee) { rr = off[ee]; off[ee] = rr + 1; }
            r.x = rr;
            e = a[i].y; rr = 0;
#pragma unroll
            for (int ee = 0; ee < NEXP; ++ee) if (e == ee) { rr = off[ee]; off[ee] = rr + 1; }
            r.y = rr;
            e = a[i].z; rr = 0;
#pragma unroll
            for (int ee = 0; ee < NEXP; ++ee) if (e == ee) { rr = off[ee]; off[ee] = rr + 1; }
            r.z = rr;
            e = a[i].w; rr = 0;
#pragma unroll
            for (int ee = 0; ee < NEXP; ++ee) if (e == ee) { rr = off[ee]; off[ee] = rr + 1; }
            r.w = rr;
            dst[i] = r;
        }

        if (lane < NEXP)
            out[lane] = (float)(tot[lane] < CAP ? tot[lane] : CAP);
    }
    __syncthreads();

    // scatter: 8192 assignments across 256 threads
    for (int a = tid; a < 2 * TOKENS; a += 256) {
        const int k = (a >= TOKENS);
        const int t = a & (TOKENS - 1);
        const int e = k ? top2[t] : top1[t];
        const int r = sr[a];
        const float p = k ? p2[t] : p1[t];
        if (r < CAP) {
            const size_t idx = ((size_t)t * NEXP + e) * CAP + r;
            out[OUT_OFS + idx] = p;
            out[OUT_OFS + (size_t)PER_OUT + idx] = (p != 0.f) ? 1.f : 0.f;
        }
    }
}

// ---------------------------------------------------------------------------
extern "C" void kernel_launch(void* const* d_in, const int* in_sizes, int n_in,
                              void* d_out, int out_size, void* d_ws, size_t ws_size,
                              hipStream_t stream) {
    const float* x  = (const float*)d_in[0];
    const float* wg = (const float*)d_in[1];
    float* out = (float*)d_out;

    int*   top1 = (int*)d_ws;
    int*   top2 = top1 + TOKENS;
    float* p1   = (float*)(top2 + TOKENS);
    float* p2   = p1 + TOKENS;

    // 1) fused: zero whole output (rocclr-shaped) + gating (hidden under fill)
    fill_gate_kernel<<<GATE_BLOCKS + FILL_BLOCKS, 256, 0, stream>>>(
        x, wg, top1, top2, p1, p2, (float4*)out);

    // 2) fused: sequential-order capacity scan + tiny scatter + header
    scan_scatter_kernel<<<1, 256, 0, stream>>>(top1, top2, p1, p2, out);
}

// Round 10
// 126.092 us; speedup vs baseline: 1.0483x; 1.0483x over previous
//
#include <hip/hip_runtime.h>
#include <math.h>

#define TOKENS   4096          // B*T = 2*2048
#define CDIM     1024
#define NEXP     8
#define CAP      2048
#define OUT_OFS  8             // used_capacity occupies d_out[0..8)
#define PER_OUT  (TOKENS * NEXP * CAP)   // 67,108,864 elements per big output

// ---------------------------------------------------------------------------
// Kernel 1: gating. One wave per token. logits[e] = dot(x[t], w_g[e]).
// Top-2 (ties -> lower index, matching lax.top_k), softmax over the two.
// ---------------------------------------------------------------------------
__global__ __launch_bounds__(256) void gating_kernel(const float* __restrict__ x,
                                                     const float* __restrict__ wg,
                                                     int*   __restrict__ top1,
                                                     int*   __restrict__ top2,
                                                     float* __restrict__ p1,
                                                     float* __restrict__ p2) {
    __shared__ float swg[NEXP * CDIM];       // 32 KiB
    for (int i = threadIdx.x; i < NEXP * CDIM / 4; i += 256)
        ((float4*)swg)[i] = ((const float4*)wg)[i];
    __syncthreads();

    const int wave = threadIdx.x >> 6;
    const int lane = threadIdx.x & 63;
    const int tok  = blockIdx.x * 4 + wave;
    const float* xr = x + (size_t)tok * CDIM;

    float acc[NEXP];
#pragma unroll
    for (int e = 0; e < NEXP; ++e) acc[e] = 0.f;

#pragma unroll
    for (int i = 0; i < CDIM / 64; ++i) {
        const float xv = xr[lane + 64 * i];
#pragma unroll
        for (int e = 0; e < NEXP; ++e)
            acc[e] = fmaf(xv, swg[e * CDIM + lane + 64 * i], acc[e]);
    }
    // 64-lane tree reduction per expert (well-conditioned, ~1e-6 abs err)
#pragma unroll
    for (int e = 0; e < NEXP; ++e) {
        float v = acc[e];
#pragma unroll
        for (int s = 32; s >= 1; s >>= 1) v += __shfl_xor(v, s, 64);
        acc[e] = v;
    }

    if (lane == 0) {
        int e1 = 0; float l1 = acc[0];
#pragma unroll
        for (int e = 1; e < NEXP; ++e)
            if (acc[e] > l1) { l1 = acc[e]; e1 = e; }
        int e2 = -1; float l2 = -INFINITY;
#pragma unroll
        for (int e = 0; e < NEXP; ++e)
            if (e != e1 && acc[e] > l2) { l2 = acc[e]; e2 = e; }
        // softmax over {l1, l2} with max subtraction (l1 >= l2)
        const float ex = expf(l2 - l1);
        const float denom = 1.f + ex;
        top1[tok] = e1;
        top2[tok] = e2;
        p1[tok] = 1.f / denom;
        p2[tok] = ex / denom;
    }
}

// ---------------------------------------------------------------------------
// Kernel 2: fused scan + scatter, one block of 256 threads (proven in R9).
// Wave 0 does the register-resident sequential-order capacity scan
// (assignment order a = k*TOKENS + t; lanes 0..31 own top1 chunks, 32..63
// top2), writing each assignment's rank into LDS sr[8192] and used_capacity
// into out[0..8). After the barrier all 256 threads scatter the <=16K
// nonzeros into the memset-zeroed buffer.
// ---------------------------------------------------------------------------
__global__ __launch_bounds__(256) void scan_scatter_kernel(const int* __restrict__ top1,
                                                           const int* __restrict__ top2,
                                                           const float* __restrict__ p1,
                                                           const float* __restrict__ p2,
                                                           float* __restrict__ out) {
    __shared__ int sr[2 * TOKENS];         // 32 KiB: rank per assignment
    const int tid = threadIdx.x;

    if (tid < 64) {
        const int lane = tid;              // 0..63
        const int* __restrict__ src = (lane < 32) ? (top1 + lane * 128)
                                                  : (top2 + (lane - 32) * 128);
        int4 a[32];
#pragma unroll
        for (int i = 0; i < 32; ++i) a[i] = ((const int4*)src)[i];

        // packed histogram: 8 experts x 8 bits (max 128 per lane fits)
        unsigned long long cnt = 0ull;
#pragma unroll
        for (int i = 0; i < 32; ++i) {
            cnt += 1ull << (a[i].x << 3);
            cnt += 1ull << (a[i].y << 3);
            cnt += 1ull << (a[i].z << 3);
            cnt += 1ull << (a[i].w << 3);
        }
        int c[NEXP];
#pragma unroll
        for (int e = 0; e < NEXP; ++e) c[e] = (int)((cnt >> (e * 8)) & 0xff);

        // per-expert exclusive prefix across lanes + totals
        int off[NEXP], tot[NEXP];
#pragma unroll
        for (int e = 0; e < NEXP; ++e) {
            int v = c[e];
#pragma unroll
            for (int s = 1; s <= 32; s <<= 1) {
                const int u = __shfl_up(v, s, 64);
                if (lane >= s) v += u;
            }
            off[e] = v - c[e];
            tot[e] = __shfl(v, 63, 64);
        }

        // replay from registers, ranks -> LDS (sr[a], a = lane*128 + j)
        int4* __restrict__ dst = (int4*)sr + lane * 32;
#pragma unroll
        for (int i = 0; i < 32; ++i) {
            int4 r;
            int e, rr;
            e = a[i].x; rr = 0;
#pragma unroll
            for (int ee = 0; ee < NEXP; ++ee) if (e == ee) { rr = off[ee]; off[ee] = rr + 1; }
            r.x = rr;
            e = a[i].y; rr = 0;
#pragma unroll
            for (int ee = 0; ee < NEXP; ++ee) if (e == ee) { rr = off[ee]; off[ee] = rr + 1; }
            r.y = rr;
            e = a[i].z; rr = 0;
#pragma unroll
            for (int ee = 0; ee < NEXP; ++ee) if (e == ee) { rr = off[ee]; off[ee] = rr + 1; }
            r.z = rr;
            e = a[i].w; rr = 0;
#pragma unroll
            for (int ee = 0; ee < NEXP; ++ee) if (e == ee) { rr = off[ee]; off[ee] = rr + 1; }
            r.w = rr;
            dst[i] = r;
        }

        if (lane < NEXP)
            out[lane] = (float)(tot[lane] < CAP ? tot[lane] : CAP);
    }
    __syncthreads();

    // scatter: 8192 assignments across 256 threads
    for (int a = tid; a < 2 * TOKENS; a += 256) {
        const int k = (a >= TOKENS);
        const int t = a & (TOKENS - 1);
        const int e = k ? top2[t] : top1[t];
        const int r = sr[a];
        const float p = k ? p2[t] : p1[t];
        if (r < CAP) {
            const size_t idx = ((size_t)t * NEXP + e) * CAP + r;
            out[OUT_OFS + idx] = p;
            out[OUT_OFS + (size_t)PER_OUT + idx] = (p != 0.f) ? 1.f : 0.f;
        }
    }
}

// ---------------------------------------------------------------------------
extern "C" void kernel_launch(void* const* d_in, const int* in_sizes, int n_in,
                              void* d_out, int out_size, void* d_ws, size_t ws_size,
                              hipStream_t stream) {
    const float* x  = (const float*)d_in[0];
    const float* wg = (const float*)d_in[1];
    float* out = (float*)d_out;

    int*   top1 = (int*)d_ws;
    int*   top2 = top1 + TOKENS;
    float* p1   = (float*)(top2 + TOKENS);
    float* p2   = p1 + TOKENS;

    // 0) zero the whole output via the runtime's memset node (graph-mode
    //    memset runs ~6 TB/s; every hand-written fill capped at ~4.3).
    hipMemsetAsync(out, 0, (size_t)(2 * PER_OUT + OUT_OFS) * sizeof(float), stream);

    // 1) gating: 4 tokens per 256-thread block
    gating_kernel<<<TOKENS / 4, 256, 0, stream>>>(x, wg, top1, top2, p1, p2);

    // 2) fused: sequential-order capacity scan + tiny scatter + header
    scan_scatter_kernel<<<1, 256, 0, stream>>>(top1, top2, p1, p2, out);
}

// Round 11
// 109.799 us; speedup vs baseline: 1.2039x; 1.1484x over previous
//
#include <hip/hip_runtime.h>
#include <math.h>

#define TOKENS   4096          // B*T = 2*2048
#define CDIM     1024
#define NEXP     8
#define CAP      2048
#define OUT_OFS  8             // used_capacity occupies d_out[0..8)
#define PER_OUT  (TOKENS * NEXP * CAP)   // 67,108,864 elements per big output

// ---------------------------------------------------------------------------
// Kernel 1: gating. One wave per token, 1024 blocks x 4 waves.
// No LDS staging (w_g is L2-hot, reads are coalesced); float4 loads.
// Top-2 (ties -> lower index, matching lax.top_k), softmax over the two.
// ---------------------------------------------------------------------------
__global__ __launch_bounds__(256) void gating_kernel(const float* __restrict__ x,
                                                     const float* __restrict__ wg,
                                                     int*   __restrict__ top1,
                                                     int*   __restrict__ top2,
                                                     float* __restrict__ p1,
                                                     float* __restrict__ p2) {
    const int wave = threadIdx.x >> 6;
    const int lane = threadIdx.x & 63;
    const int tok  = blockIdx.x * 4 + wave;

    const float4* __restrict__ xr = (const float4*)(x + (size_t)tok * CDIM);
    float4 xv[4];
#pragma unroll
    for (int i = 0; i < 4; ++i) xv[i] = xr[lane + 64 * i];

    float acc[NEXP];
#pragma unroll
    for (int e = 0; e < NEXP; ++e) acc[e] = 0.f;

#pragma unroll
    for (int e = 0; e < NEXP; ++e) {
        const float4* __restrict__ wr = (const float4*)(wg + e * CDIM);
#pragma unroll
        for (int i = 0; i < 4; ++i) {
            const float4 w = wr[lane + 64 * i];
            acc[e] = fmaf(xv[i].x, w.x, acc[e]);
            acc[e] = fmaf(xv[i].y, w.y, acc[e]);
            acc[e] = fmaf(xv[i].z, w.z, acc[e]);
            acc[e] = fmaf(xv[i].w, w.w, acc[e]);
        }
    }
    // 64-lane tree reduction per expert (well-conditioned, ~1e-6 abs err)
#pragma unroll
    for (int e = 0; e < NEXP; ++e) {
        float v = acc[e];
#pragma unroll
        for (int s = 32; s >= 1; s >>= 1) v += __shfl_xor(v, s, 64);
        acc[e] = v;
    }

    if (lane == 0) {
        int e1 = 0; float l1 = acc[0];
#pragma unroll
        for (int e = 1; e < NEXP; ++e)
            if (acc[e] > l1) { l1 = acc[e]; e1 = e; }
        int e2 = -1; float l2 = -INFINITY;
#pragma unroll
        for (int e = 0; e < NEXP; ++e)
            if (e != e1 && acc[e] > l2) { l2 = acc[e]; e2 = e; }
        // softmax over {l1, l2} with max subtraction (l1 >= l2)
        const float ex = expf(l2 - l1);
        const float denom = 1.f + ex;
        top1[tok] = e1;
        top2[tok] = e2;
        p1[tok] = 1.f / denom;
        p2[tok] = ex / denom;
    }
}

// ---------------------------------------------------------------------------
// Kernel 2: wide fused scan + scatter, 32 blocks x 256 threads.
// Each block's wave 0 REDUNDANTLY computes the full sequential-order
// capacity scan (register-resident, identical algorithm to R8; inputs are
// 16 KB of L2-broadcast reads, so the redundancy is free in wall time) into
// LDS sr[8192]. After the barrier, block b scatters assignments
// [b*256, (b+1)*256) — one store pair per thread, spread over 32 CUs.
// Block 0 also writes the used_capacity header. One dispatch, no spin.
// ---------------------------------------------------------------------------
__global__ __launch_bounds__(256) void scan_scatter_kernel(const int* __restrict__ top1,
                                                           const int* __restrict__ top2,
                                                           const float* __restrict__ p1,
                                                           const float* __restrict__ p2,
                                                           float* __restrict__ out) {
    __shared__ int sr[2 * TOKENS];         // 32 KiB: rank per assignment
    const int tid = threadIdx.x;

    if (tid < 64) {
        const int lane = tid;              // 0..63; 0..31 -> top1 chunks, 32..63 -> top2
        const int* __restrict__ src = (lane < 32) ? (top1 + lane * 128)
                                                  : (top2 + (lane - 32) * 128);
        int4 a[32];
#pragma unroll
        for (int i = 0; i < 32; ++i) a[i] = ((const int4*)src)[i];

        // packed histogram: 8 experts x 8 bits (max 128 per lane fits)
        unsigned long long cnt = 0ull;
#pragma unroll
        for (int i = 0; i < 32; ++i) {
            cnt += 1ull << (a[i].x << 3);
            cnt += 1ull << (a[i].y << 3);
            cnt += 1ull << (a[i].z << 3);
            cnt += 1ull << (a[i].w << 3);
        }
        int c[NEXP];
#pragma unroll
        for (int e = 0; e < NEXP; ++e) c[e] = (int)((cnt >> (e * 8)) & 0xff);

        // per-expert exclusive prefix across lanes + totals
        int off[NEXP], tot[NEXP];
#pragma unroll
        for (int e = 0; e < NEXP; ++e) {
            int v = c[e];
#pragma unroll
            for (int s = 1; s <= 32; s <<= 1) {
                const int u = __shfl_up(v, s, 64);
                if (lane >= s) v += u;
            }
            off[e] = v - c[e];
            tot[e] = __shfl(v, 63, 64);
        }

        // replay from registers, ranks -> LDS (sr[a], a = lane*128 + j)
        int4* __restrict__ dst = (int4*)sr + lane * 32;
#pragma unroll
        for (int i = 0; i < 32; ++i) {
            int4 r;
            int e, rr;
            e = a[i].x; rr = 0;
#pragma unroll
            for (int ee = 0; ee < NEXP; ++ee) if (e == ee) { rr = off[ee]; off[ee] = rr + 1; }
            r.x = rr;
            e = a[i].y; rr = 0;
#pragma unroll
            for (int ee = 0; ee < NEXP; ++ee) if (e == ee) { rr = off[ee]; off[ee] = rr + 1; }
            r.y = rr;
            e = a[i].z; rr = 0;
#pragma unroll
            for (int ee = 0; ee < NEXP; ++ee) if (e == ee) { rr = off[ee]; off[ee] = rr + 1; }
            r.z = rr;
            e = a[i].w; rr = 0;
#pragma unroll
            for (int ee = 0; ee < NEXP; ++ee) if (e == ee) { rr = off[ee]; off[ee] = rr + 1; }
            r.w = rr;
            dst[i] = r;
        }

        if (blockIdx.x == 0 && lane < NEXP)
            out[lane] = (float)(tot[lane] < CAP ? tot[lane] : CAP);
    }
    __syncthreads();

    // scatter: one assignment per thread, 32 blocks cover all 8192
    const int a = blockIdx.x * 256 + tid;
    const int k = (a >= TOKENS);
    const int t = a & (TOKENS - 1);
    const int e = k ? top2[t] : top1[t];
    const int r = sr[a];
    const float p = k ? p2[t] : p1[t];
    if (r < CAP) {
        const size_t idx = ((size_t)t * NEXP + e) * CAP + r;
        out[OUT_OFS + idx] = p;
        out[OUT_OFS + (size_t)PER_OUT + idx] = (p != 0.f) ? 1.f : 0.f;
    }
}

// ---------------------------------------------------------------------------
extern "C" void kernel_launch(void* const* d_in, const int* in_sizes, int n_in,
                              void* d_out, int out_size, void* d_ws, size_t ws_size,
                              hipStream_t stream) {
    const float* x  = (const float*)d_in[0];
    const float* wg = (const float*)d_in[1];
    float* out = (float*)d_out;

    int*   top1 = (int*)d_ws;
    int*   top2 = top1 + TOKENS;
    float* p1   = (float*)(top2 + TOKENS);
    float* p2   = p1 + TOKENS;

    // 0) zero the whole output via the runtime's memset node (graph-mode
    //    memset ~6 TB/s; every hand-written fill capped at ~4.3 TB/s).
    hipMemsetAsync(out, 0, (size_t)(2 * PER_OUT + OUT_OFS) * sizeof(float), stream);

    // 1) gating: 4 tokens per 256-thread block, no LDS, float4 loads
    gating_kernel<<<TOKENS / 4, 256, 0, stream>>>(x, wg, top1, top2, p1, p2);

    // 2) wide fused: redundant per-block scan + 1-store-per-thread scatter
    scan_scatter_kernel<<<2 * TOKENS / 256, 256, 0, stream>>>(top1, top2, p1, p2, out);
}

// Round 13
// 109.739 us; speedup vs baseline: 1.2045x; 1.0005x over previous
//
#include <hip/hip_runtime.h>
#include <math.h>

#define TOKENS   4096          // B*T = 2*2048
#define CDIM     1024
#define NEXP     8
#define CAP      2048
#define OUT_OFS  8             // used_capacity occupies d_out[0..8)
#define PER_OUT  (TOKENS * NEXP * CAP)   // 67,108,864 elements per big output

// ---------------------------------------------------------------------------
// Kernel 1: gating. One wave per token, 1024 blocks x 4 waves.
// No LDS staging (w_g is L2-hot, reads are coalesced); float4 loads.
// Top-2 (ties -> lower index, matching lax.top_k), softmax over the two.
// ---------------------------------------------------------------------------
__global__ __launch_bounds__(256) void gating_kernel(const float* __restrict__ x,
                                                     const float* __restrict__ wg,
                                                     int*   __restrict__ top1,
                                                     int*   __restrict__ top2,
                                                     float* __restrict__ p1,
                                                     float* __restrict__ p2) {
    const int wave = threadIdx.x >> 6;
    const int lane = threadIdx.x & 63;
    const int tok  = blockIdx.x * 4 + wave;

    const float4* __restrict__ xr = (const float4*)(x + (size_t)tok * CDIM);
    float4 xv[4];
#pragma unroll
    for (int i = 0; i < 4; ++i) xv[i] = xr[lane + 64 * i];

    float acc[NEXP];
#pragma unroll
    for (int e = 0; e < NEXP; ++e) acc[e] = 0.f;

#pragma unroll
    for (int e = 0; e < NEXP; ++e) {
        const float4* __restrict__ wr = (const float4*)(wg + e * CDIM);
#pragma unroll
        for (int i = 0; i < 4; ++i) {
            const float4 w = wr[lane + 64 * i];
            acc[e] = fmaf(xv[i].x, w.x, acc[e]);
            acc[e] = fmaf(xv[i].y, w.y, acc[e]);
            acc[e] = fmaf(xv[i].z, w.z, acc[e]);
            acc[e] = fmaf(xv[i].w, w.w, acc[e]);
        }
    }
    // 64-lane tree reduction per expert (well-conditioned, ~1e-6 abs err)
#pragma unroll
    for (int e = 0; e < NEXP; ++e) {
        float v = acc[e];
#pragma unroll
        for (int s = 32; s >= 1; s >>= 1) v += __shfl_xor(v, s, 64);
        acc[e] = v;
    }

    if (lane == 0) {
        int e1 = 0; float l1 = acc[0];
#pragma unroll
        for (int e = 1; e < NEXP; ++e)
            if (acc[e] > l1) { l1 = acc[e]; e1 = e; }
        int e2 = -1; float l2 = -INFINITY;
#pragma unroll
        for (int e = 0; e < NEXP; ++e)
            if (e != e1 && acc[e] > l2) { l2 = acc[e]; e2 = e; }
        // softmax over {l1, l2} with max subtraction (l1 >= l2)
        const float ex = expf(l2 - l1);
        const float denom = 1.f + ex;
        top1[tok] = e1;
        top2[tok] = e2;
        p1[tok] = 1.f / denom;
        p2[tok] = ex / denom;
    }
}

// ---------------------------------------------------------------------------
// Kernel 2: wide fused scan + scatter, 32 blocks x 256 threads.
// Each block's wave 0 REDUNDANTLY computes the full sequential-order
// capacity scan (register-resident; inputs are 16 KB of L2-broadcast reads,
// so the redundancy is free in wall time) into LDS sr[8192]. After the
// barrier, block b scatters assignments [b*256, (b+1)*256) — one store pair
// per thread, spread over 32 CUs. Block 0 writes the used_capacity header.
// ---------------------------------------------------------------------------
__global__ __launch_bounds__(256) void scan_scatter_kernel(const int* __restrict__ top1,
                                                           const int* __restrict__ top2,
                                                           const float* __restrict__ p1,
                                                           const float* __restrict__ p2,
                                                           float* __restrict__ out) {
    __shared__ int sr[2 * TOKENS];         // 32 KiB: rank per assignment
    const int tid = threadIdx.x;

    if (tid < 64) {
        const int lane = tid;              // 0..31 -> top1 chunks, 32..63 -> top2
        const int* __restrict__ src = (lane < 32) ? (top1 + lane * 128)
                                                  : (top2 + (lane - 32) * 128);
        int4 a[32];
#pragma unroll
        for (int i = 0; i < 32; ++i) a[i] = ((const int4*)src)[i];

        // packed histogram: 8 experts x 8 bits (max 128 per lane fits)
        unsigned long long cnt = 0ull;
#pragma unroll
        for (int i = 0; i < 32; ++i) {
            cnt += 1ull << (a[i].x << 3);
            cnt += 1ull << (a[i].y << 3);
            cnt += 1ull << (a[i].z << 3);
            cnt += 1ull << (a[i].w << 3);
        }
        int c[NEXP];
#pragma unroll
        for (int e = 0; e < NEXP; ++e) c[e] = (int)((cnt >> (e * 8)) & 0xff);

        // per-expert exclusive prefix across lanes + totals
        int off[NEXP], tot[NEXP];
#pragma unroll
        for (int e = 0; e < NEXP; ++e) {
            int v = c[e];
#pragma unroll
            for (int s = 1; s <= 32; s <<= 1) {
                const int u = __shfl_up(v, s, 64);
                if (lane >= s) v += u;
            }
            off[e] = v - c[e];
            tot[e] = __shfl(v, 63, 64);
        }

        // replay from registers, ranks -> LDS (sr[a], a = lane*128 + j)
        int4* __restrict__ dst = (int4*)sr + lane * 32;
#pragma unroll
        for (int i = 0; i < 32; ++i) {
            int4 r;
            int e, rr;
            e = a[i].x; rr = 0;
#pragma unroll
            for (int ee = 0; ee < NEXP; ++ee) if (e == ee) { rr = off[ee]; off[ee] = rr + 1; }
            r.x = rr;
            e = a[i].y; rr = 0;
#pragma unroll
            for (int ee = 0; ee < NEXP; ++ee) if (e == ee) { rr = off[ee]; off[ee] = rr + 1; }
            r.y = rr;
            e = a[i].z; rr = 0;
#pragma unroll
            for (int ee = 0; ee < NEXP; ++ee) if (e == ee) { rr = off[ee]; off[ee] = rr + 1; }
            r.z = rr;
            e = a[i].w; rr = 0;
#pragma unroll
            for (int ee = 0; ee < NEXP; ++ee) if (e == ee) { rr = off[ee]; off[ee] = rr + 1; }
            r.w = rr;
            dst[i] = r;
        }

        if (blockIdx.x == 0 && lane < NEXP)
            out[lane] = (float)(tot[lane] < CAP ? tot[lane] : CAP);
    }
    __syncthreads();

    // scatter: one assignment per thread, 32 blocks cover all 8192
    const int a = blockIdx.x * 256 + tid;
    const int k = (a >= TOKENS);
    const int t = a & (TOKENS - 1);
    const int e = k ? top2[t] : top1[t];
    const int r = sr[a];
    const float p = k ? p2[t] : p1[t];
    if (r < CAP) {
        const size_t idx = ((size_t)t * NEXP + e) * CAP + r;
        out[OUT_OFS + idx] = p;
        out[OUT_OFS + (size_t)PER_OUT + idx] = (p != 0.f) ? 1.f : 0.f;
    }
}

// ---------------------------------------------------------------------------
extern "C" void kernel_launch(void* const* d_in, const int* in_sizes, int n_in,
                              void* d_out, int out_size, void* d_ws, size_t ws_size,
                              hipStream_t stream) {
    const float* x  = (const float*)d_in[0];
    const float* wg = (const float*)d_in[1];
    float* out = (float*)d_out;

    int*   top1 = (int*)d_ws;
    int*   top2 = top1 + TOKENS;
    float* p1   = (float*)(top2 + TOKENS);
    float* p2   = p1 + TOKENS;

    // 0) zero the whole output via the runtime's memset node (graph-mode
    //    memset ~5.8 TB/s; every hand-written fill capped at ~4.3 TB/s).
    hipMemsetAsync(out, 0, (size_t)(2 * PER_OUT + OUT_OFS) * sizeof(float), stream);

    // 1) gating: 4 tokens per 256-thread block, no LDS, float4 loads
    gating_kernel<<<TOKENS / 4, 256, 0, stream>>>(x, wg, top1, top2, p1, p2);

    // 2) wide fused: redundant per-block scan + 1-store-per-thread scatter
    scan_scatter_kernel<<<2 * TOKENS / 256, 256, 0, stream>>>(top1, top2, p1, p2, out);
}